// Round 8
// baseline (2480.296 us; speedup 1.0000x reference)
//
#include <hip/hip_runtime.h>

// GRU decoder, bf16 MFMA. R8: spill elimination via block size.
// Allocator evidence across R2-R7: unified reg budget = 65536/block_size
// (launch_bounds 2nd arg ignored). 256-thr blocks -> 256 regs/thread.
// BM=16 rows/block, 512 blocks (2/CU), 4 waves/block; wave w owns cols
// [w*64, w*64+64) per gate (12 B-frags/kt). Unified demand ~174 < 256.
// Cold constants (biases, Wk row0, dense_w, init prev) live in LDS.
// Weights streamed from L2 as swizzled B-fragments; unified 10-K-tile loop
// (kt 0..7 h@Wr from hs, kt 8..9 feat@Wk from xs); prev_out rank-1 term
// folded into accumulator init; h fp32 in regs + bf16 in LDS.

#define Bdim 8192
#define Tdim 96
#define Fdim 64
#define Hdim 256
#define BM   16
#define XS   72    // feat row stride (bf16): 64 + 8 pad
#define HS   264   // h row stride (bf16): 256 + 8 pad
#define OS   97    // outbuf row stride (floats)

typedef __attribute__((ext_vector_type(8))) short s16x8;
typedef __attribute__((ext_vector_type(4))) float f32x4;

#define MFMA __builtin_amdgcn_mfma_f32_16x16x32_bf16

__device__ __forceinline__ unsigned short f2bf(float f) {
    union { float f; unsigned u; } v; v.f = f;
    unsigned r = v.u + 0x7FFFu + ((v.u >> 16) & 1u);   // RNE
    return (unsigned short)(r >> 16);
}

// ---- one-time weight conversion + B-fragment swizzle ----
// frag f = (w*10 + kt)*12 + g*4 + n4, lane l: 8 bf16 at sW[f*512 + l*8].
// lane holds B[k][n], k = kt*32 + (l>>4)*8 + j, n = g*256 + w*64 + n4*16 + (l&15).
// kt 0..7: row k of Wr; kt 8..9: row 1 + (kt-8)*32 + (l>>4)*8 + j of Wk.
__global__ void prep_swz(const float* __restrict__ Wk, const float* __restrict__ Wr,
                         unsigned short* __restrict__ sW) {
    int idx = blockIdx.x * blockDim.x + threadIdx.x;
    if (idx >= 480 * 64) return;
    int lane = idx & 63, f = idx >> 6;
    int n4 = f & 3;
    int g  = (f >> 2) % 3;
    int kt = (f / 12) % 10;
    int w  = f / 120;
    int q = lane >> 4, cc = lane & 15;
    int n = g * 256 + w * 64 + n4 * 16 + cc;
    unsigned short* d = sW + (size_t)idx * 8;
#pragma unroll
    for (int j = 0; j < 8; ++j) {
        float v;
        if (kt < 8) v = Wr[(size_t)(kt * 32 + q * 8 + j) * 768 + n];
        else        v = Wk[(size_t)(1 + (kt - 8) * 32 + q * 8 + j) * 768 + n];
        d[j] = f2bf(v);
    }
}

__launch_bounds__(256)
__global__ void gru_mfma7(
    const float* __restrict__ feat,       // [B,T,F]
    const float* __restrict__ init_state, // [B,H]
    const float* __restrict__ init_inp,   // [B,1]
    const unsigned short* __restrict__ sW,
    const float* __restrict__ Wk,         // row 0 (prev_out rank-1 term)
    const float* __restrict__ ib, const float* __restrict__ rb,
    const float* __restrict__ dw, const float* __restrict__ db,
    float* __restrict__ out)              // [B,T,1]
{
    __shared__ __align__(16) unsigned short xs[BM * XS];  // feat tile, bf16
    __shared__ __align__(16) unsigned short hs[BM * HS];  // h state, bf16
    __shared__ float wpart[2][4][BM];                     // dbl-buffered by t&1
    __shared__ float outbuf[BM * OS];
    __shared__ float wk0s[768];    // Wk row 0
    __shared__ float dws[Hdim];    // dense_w
    __shared__ float biasL[1024];  // [0:256)=bz, [256:512)=brr, [512:768)=bxh, [768:1024)=bhh
    __shared__ float prevs[BM];    // init_inp

    const int tid  = threadIdx.x;
    const int lane = tid & 63;
    const int w    = tid >> 6;     // wave 0..3: cols [w*64, w*64+64) per gate
    const int q    = lane >> 4;
    const int c    = lane & 15;
    const int b0   = blockIdx.x * BM;

    // ---- stage constants into LDS ----
    for (int i = tid; i < 768; i += 256) wk0s[i] = Wk[i];
    dws[tid] = dw[tid];
    {
        int i = tid;
        biasL[i]       = ib[i]       + rb[i];        // bz
        biasL[256 + i] = ib[256 + i] + rb[256 + i];  // brr
        biasL[512 + i] = ib[512 + i];                // bxh
        biasL[768 + i] = rb[512 + i];                // bhh
    }
    if (tid < BM) prevs[tid] = init_inp[b0 + tid];
    const float dbv = db[0];

    // init h: fp32 in regs + bf16 in LDS
    float hreg[4][4];   // [n4][i]
#pragma unroll
    for (int n4 = 0; n4 < 4; ++n4)
#pragma unroll
        for (int i = 0; i < 4; ++i) {
            int row = q * 4 + i;
            int col = w * 64 + n4 * 16 + c;
            float v = init_state[(size_t)(b0 + row) * Hdim + col];
            hreg[n4][i] = v;
            hs[row * HS + col] = f2bf(v);
        }

    // stage feat t=0 (256 threads = 16 rows x 16 float4)
    {
        int r = tid >> 4, fi = tid & 15;
        float4 f = *(const float4*)&feat[((size_t)(b0 + r) * Tdim + 0) * Fdim + fi * 4];
        ushort4 p; p.x = f2bf(f.x); p.y = f2bf(f.y); p.z = f2bf(f.z); p.w = f2bf(f.w);
        *(ushort4*)&xs[r * XS + fi * 4] = p;
    }

    const unsigned short* wp0 = sW + (size_t)(w * 120) * 512 + lane * 8;

    __syncthreads();

    for (int t = 0; t < Tdim; ++t) {
        // ---- prev_out for this step (wpart[(t-1)&1] visible since last barrier) ----
        float pv[4];
        if (t == 0) {
#pragma unroll
            for (int i = 0; i < 4; ++i) pv[i] = prevs[q * 4 + i];
        } else {
            int r = lane & 15;
            const float (*wp)[BM] = wpart[(t - 1) & 1];
            float s = dbv + wp[0][r] + wp[1][r] + wp[2][r] + wp[3][r];
            if (w == 0 && lane < BM) outbuf[r * OS + (t - 1)] = s;
#pragma unroll
            for (int i = 0; i < 4; ++i) pv[i] = __shfl(s, q * 4 + i, 64);
        }

        // ---- accumulator init: bias + prev_out rank-1 term ----
        f32x4 az[4], arr[4], axh[4], ahh[4];
#pragma unroll
        for (int n4 = 0; n4 < 4; ++n4) {
            int col = w * 64 + n4 * 16 + c;
            float bzv = biasL[col], brv = biasL[256 + col];
            float bxv = biasL[512 + col], bhv = biasL[768 + col];
            float wz = wk0s[col], wr_ = wk0s[256 + col], wh = wk0s[512 + col];
#pragma unroll
            for (int i = 0; i < 4; ++i) {
                az[n4][i]  = bzv + pv[i] * wz;
                arr[n4][i] = brv + pv[i] * wr_;
                axh[n4][i] = bxv + pv[i] * wh;
                ahh[n4][i] = bhv;
            }
        }

        // ---- unified K-loop: kt 0..7 from hs (Wr), kt 8..9 from xs (Wk) ----
#pragma unroll
        for (int kt = 0; kt < 10; ++kt) {
            const unsigned short* fp = wp0 + (size_t)(kt * 12) * 512;
            s16x8 b[12];
#pragma unroll
            for (int u = 0; u < 12; ++u) b[u] = *(const s16x8*)(fp + u * 512);
            s16x8 a;
            if (kt < 8) a = *(const s16x8*)&hs[c * HS + kt * 32 + q * 8];
            else        a = *(const s16x8*)&xs[c * XS + (kt - 8) * 32 + q * 8];
#pragma unroll
            for (int n4 = 0; n4 < 4; ++n4) az[n4]  = MFMA(a, b[n4],     az[n4], 0, 0, 0);
#pragma unroll
            for (int n4 = 0; n4 < 4; ++n4) arr[n4] = MFMA(a, b[4 + n4], arr[n4], 0, 0, 0);
            if (kt < 8) {
#pragma unroll
                for (int n4 = 0; n4 < 4; ++n4) ahh[n4] = MFMA(a, b[8 + n4], ahh[n4], 0, 0, 0);
            } else {
#pragma unroll
                for (int n4 = 0; n4 < 4; ++n4) axh[n4] = MFMA(a, b[8 + n4], axh[n4], 0, 0, 0);
            }
        }
        __syncthreads();   // S1: all hs/xs reads of this step done

        // ---- epilogue: gates, h update, dense partials ----
        float sd[4] = {0.0f, 0.0f, 0.0f, 0.0f};
#pragma unroll
        for (int n4 = 0; n4 < 4; ++n4) {
            int col = w * 64 + n4 * 16 + c;
            float dv = dws[col];
#pragma unroll
            for (int i = 0; i < 4; ++i) {
                float zz = 1.0f / (1.0f + __expf(-az[n4][i]));
                float rr = 1.0f / (1.0f + __expf(-arr[n4][i]));
                float cd = tanhf(axh[n4][i] + rr * ahh[n4][i]);
                float hn = zz * hreg[n4][i] + (1.0f - zz) * cd;
                hreg[n4][i] = hn;
                hs[(q * 4 + i) * HS + col] = f2bf(hn);
                sd[i] += hn * dv;
            }
        }
#pragma unroll
        for (int i = 0; i < 4; ++i) {
            float s = sd[i];
            s += __shfl_xor(s, 1, 64);
            s += __shfl_xor(s, 2, 64);
            s += __shfl_xor(s, 4, 64);
            s += __shfl_xor(s, 8, 64);
            if (c == 0) wpart[t & 1][w][q * 4 + i] = s;
        }

        // stage feat t+1 (xs reads for step t finished at S1)
        if (t + 1 < Tdim) {
            int r = tid >> 4, fi = tid & 15;
            float4 f = *(const float4*)&feat[((size_t)(b0 + r) * Tdim + (t + 1)) * Fdim + fi * 4];
            ushort4 p; p.x = f2bf(f.x); p.y = f2bf(f.y); p.z = f2bf(f.z); p.w = f2bf(f.w);
            *(ushort4*)&xs[r * XS + fi * 4] = p;
        }
        __syncthreads();   // S2: hs/wpart/xs writes visible
    }

    // final dense output for t=95
    {
        int r = lane & 15;
        const float (*wp)[BM] = wpart[(Tdim - 1) & 1];
        float s = dbv + wp[0][r] + wp[1][r] + wp[2][r] + wp[3][r];
        if (w == 0 && lane < BM) outbuf[r * OS + (Tdim - 1)] = s;
    }
    __syncthreads();

    // coalesced dump: out[(b0+r)*96 + tt]
    for (int i = tid; i < BM * Tdim; i += 256) {
        int r = i / Tdim, tt = i - r * Tdim;
        out[(size_t)b0 * Tdim + i] = outbuf[r * OS + tt];
    }
}

extern "C" void kernel_launch(void* const* d_in, const int* in_sizes, int n_in,
                              void* d_out, int out_size, void* d_ws, size_t ws_size,
                              hipStream_t stream) {
    const float* feat       = (const float*)d_in[0];
    const float* init_state = (const float*)d_in[1];
    const float* init_inp   = (const float*)d_in[2];
    const float* Wk         = (const float*)d_in[3];
    const float* Wr         = (const float*)d_in[4];
    const float* ib         = (const float*)d_in[5];
    const float* rb         = (const float*)d_in[6];
    const float* dw         = (const float*)d_in[7];
    const float* db         = (const float*)d_in[8];
    float* out              = (float*)d_out;

    unsigned short* sW = (unsigned short*)d_ws;   // 480 frags * 1 KB = 480 KB

    prep_swz<<<120, 256, 0, stream>>>(Wk, Wr, sW);
    gru_mfma7<<<Bdim / BM, 256, 0, stream>>>(
        feat, init_state, init_inp, sW, Wk, ib, rb, dw, db, out);
}

// Round 9
// 1909.927 us; speedup vs baseline: 1.2986x; 1.2986x over previous
//
#include <hip/hip_runtime.h>

// GRU decoder, bf16 MFMA. R9: no-spill + 4 waves/SIMD simultaneously.
// Measured allocator rule: reg cap = 65536/block_size (launch_bounds 2nd arg
// ignored). 512-thr block -> 128-reg cap; per-thread demand ~105 (BM=16,
// 6 N-tiles/wave, consts in LDS) -> no spills AND 4 waves/SIMD.
// Grid = 512 blocks (BM=16 rows each) = 2 blocks/CU interleaving at barriers.
// Weights streamed from L2 as swizzled B-fragments (same sW layout as R6);
// unified 10-K-tile loop (kt 0..7 h@Wr from hs, kt 8..9 feat@Wk from xs);
// prev_out rank-1 term folded into accumulator init; h fp32 in regs + bf16
// copy in LDS for next step's A-fragments.

#define Bdim 8192
#define Tdim 96
#define Fdim 64
#define Hdim 256
#define BM   16
#define XS   72    // feat row stride (bf16): 64 + 8 pad
#define HS   264   // h row stride (bf16): 256 + 8 pad
#define OS   97    // outbuf row stride (floats)

typedef __attribute__((ext_vector_type(8))) short s16x8;
typedef __attribute__((ext_vector_type(4))) float f32x4;

#define MFMA __builtin_amdgcn_mfma_f32_16x16x32_bf16

__device__ __forceinline__ unsigned short f2bf(float f) {
    union { float f; unsigned u; } v; v.f = f;
    unsigned r = v.u + 0x7FFFu + ((v.u >> 16) & 1u);   // RNE
    return (unsigned short)(r >> 16);
}

// ---- one-time weight conversion + B-fragment swizzle (same as R6) ----
// frag f = ((w*10 + kt)*3 + g)*2 + n2, lane l: 8 bf16 at sW[f*512 + l*8].
// lane holds B[k][n], k = kt*32 + (l>>4)*8 + j, n = g*256 + w*32 + n2*16 + (l&15).
// kt 0..7: B row k of Wr; kt 8..9: B row 1 + (kt-8)*32 + (l>>4)*8 + j of Wk.
__global__ void prep_swz(const float* __restrict__ Wk, const float* __restrict__ Wr,
                         unsigned short* __restrict__ sW) {
    int idx = blockIdx.x * blockDim.x + threadIdx.x;
    if (idx >= 480 * 64) return;
    int lane = idx & 63, f = idx >> 6;
    int n2 = f & 1;
    int g  = (f >> 1) % 3;
    int kt = (f / 6) % 10;
    int w  = f / 60;
    int q = lane >> 4, cc = lane & 15;
    int n = g * 256 + w * 32 + n2 * 16 + cc;
    unsigned short* d = sW + (size_t)idx * 8;
#pragma unroll
    for (int j = 0; j < 8; ++j) {
        float v;
        if (kt < 8) v = Wr[(size_t)(kt * 32 + q * 8 + j) * 768 + n];
        else        v = Wk[(size_t)(1 + (kt - 8) * 32 + q * 8 + j) * 768 + n];
        d[j] = f2bf(v);
    }
}

__launch_bounds__(512)
__global__ void gru_mfma8(
    const float* __restrict__ feat,       // [B,T,F]
    const float* __restrict__ init_state, // [B,H]
    const float* __restrict__ init_inp,   // [B,1]
    const unsigned short* __restrict__ sW,
    const float* __restrict__ Wk,         // row 0 (prev_out rank-1 term)
    const float* __restrict__ ib, const float* __restrict__ rb,
    const float* __restrict__ dw, const float* __restrict__ db,
    float* __restrict__ out)              // [B,T,1]
{
    __shared__ __align__(16) unsigned short xs[BM * XS];  // feat tile, bf16
    __shared__ __align__(16) unsigned short hs[BM * HS];  // h state, bf16
    __shared__ float wpart[2][8][BM];                     // dbl-buffered by t&1
    __shared__ float outbuf[BM * OS];
    __shared__ float wk0s[768];    // Wk row 0
    __shared__ float dws[Hdim];    // dense_w
    __shared__ float biasL[1024];  // [0:256)=bz [256:512)=brr [512:768)=bxh [768:1024)=bhh
    __shared__ float prevs[BM];    // init_inp

    const int tid  = threadIdx.x;
    const int lane = tid & 63;
    const int w    = tid >> 6;     // wave 0..7: cols [w*32, w*32+32) per gate
    const int q    = lane >> 4;
    const int c    = lane & 15;
    const int b0   = blockIdx.x * BM;

    // ---- stage constants into LDS ----
    for (int i = tid; i < 768; i += 512) wk0s[i] = Wk[i];
    if (tid < 256) {
        dws[tid] = dw[tid];
        biasL[tid]       = ib[tid]       + rb[tid];        // bz
        biasL[256 + tid] = ib[256 + tid] + rb[256 + tid];  // brr
        biasL[512 + tid] = ib[512 + tid];                  // bxh
        biasL[768 + tid] = rb[512 + tid];                  // bhh
    }
    if (tid < BM) prevs[tid] = init_inp[b0 + tid];
    const float dbv = db[0];

    // init h: fp32 in regs + bf16 in LDS (rows q*4+i, cols w*32+n2*16+c)
    float hreg[2][4];   // [n2][i]
#pragma unroll
    for (int n2 = 0; n2 < 2; ++n2)
#pragma unroll
        for (int i = 0; i < 4; ++i) {
            int row = q * 4 + i;
            int col = w * 32 + n2 * 16 + c;
            float v = init_state[(size_t)(b0 + row) * Hdim + col];
            hreg[n2][i] = v;
            hs[row * HS + col] = f2bf(v);
        }

    // stage feat t=0 (256 threads: 16 rows x 16 float4)
    if (tid < 256) {
        int r = tid >> 4, fi = tid & 15;
        float4 f = *(const float4*)&feat[((size_t)(b0 + r) * Tdim + 0) * Fdim + fi * 4];
        ushort4 p; p.x = f2bf(f.x); p.y = f2bf(f.y); p.z = f2bf(f.z); p.w = f2bf(f.w);
        *(ushort4*)&xs[r * XS + fi * 4] = p;
    }

    const unsigned short* wp0 = sW + (size_t)(w * 60) * 512 + lane * 8;

    __syncthreads();

    for (int t = 0; t < Tdim; ++t) {
        // ---- prev_out for this step ----
        float pv[4];
        if (t == 0) {
#pragma unroll
            for (int i = 0; i < 4; ++i) pv[i] = prevs[q * 4 + i];
        } else {
            int r = lane & 15;
            const float (*wp)[BM] = wpart[(t - 1) & 1];
            float s = dbv;
#pragma unroll
            for (int ww = 0; ww < 8; ++ww) s += wp[ww][r];
            if (w == 0 && lane < BM) outbuf[r * OS + (t - 1)] = s;
#pragma unroll
            for (int i = 0; i < 4; ++i) pv[i] = __shfl(s, q * 4 + i, 64);
        }

        // ---- accumulator init: bias + prev_out rank-1 term ----
        f32x4 az[2], arr[2], axh[2], ahh[2];
#pragma unroll
        for (int n2 = 0; n2 < 2; ++n2) {
            int col = w * 32 + n2 * 16 + c;
            float bzv = biasL[col], brv = biasL[256 + col];
            float bxv = biasL[512 + col], bhv = biasL[768 + col];
            float wz = wk0s[col], wr_ = wk0s[256 + col], wh = wk0s[512 + col];
#pragma unroll
            for (int i = 0; i < 4; ++i) {
                az[n2][i]  = bzv + pv[i] * wz;
                arr[n2][i] = brv + pv[i] * wr_;
                axh[n2][i] = bxv + pv[i] * wh;
                ahh[n2][i] = bhv;
            }
        }

        // ---- unified K-loop: kt 0..7 from hs (Wr), kt 8..9 from xs (Wk) ----
#pragma unroll
        for (int kt = 0; kt < 10; ++kt) {
            const unsigned short* fp = wp0 + (size_t)(kt * 6) * 512;
            s16x8 b0f = *(const s16x8*)(fp + 0 * 512);
            s16x8 b1f = *(const s16x8*)(fp + 1 * 512);
            s16x8 b2f = *(const s16x8*)(fp + 2 * 512);
            s16x8 b3f = *(const s16x8*)(fp + 3 * 512);
            s16x8 b4f = *(const s16x8*)(fp + 4 * 512);
            s16x8 b5f = *(const s16x8*)(fp + 5 * 512);
            s16x8 a;
            if (kt < 8) a = *(const s16x8*)&hs[c * HS + kt * 32 + q * 8];
            else        a = *(const s16x8*)&xs[c * XS + (kt - 8) * 32 + q * 8];
            az[0]  = MFMA(a, b0f, az[0], 0, 0, 0);
            az[1]  = MFMA(a, b1f, az[1], 0, 0, 0);
            arr[0] = MFMA(a, b2f, arr[0], 0, 0, 0);
            arr[1] = MFMA(a, b3f, arr[1], 0, 0, 0);
            if (kt < 8) {
                ahh[0] = MFMA(a, b4f, ahh[0], 0, 0, 0);
                ahh[1] = MFMA(a, b5f, ahh[1], 0, 0, 0);
            } else {
                axh[0] = MFMA(a, b4f, axh[0], 0, 0, 0);
                axh[1] = MFMA(a, b5f, axh[1], 0, 0, 0);
            }
        }
        __syncthreads();   // S1: all hs/xs reads of this step done

        // ---- epilogue: gates, h update, dense partials ----
        float sd[4] = {0.0f, 0.0f, 0.0f, 0.0f};
#pragma unroll
        for (int n2 = 0; n2 < 2; ++n2) {
            int col = w * 32 + n2 * 16 + c;
            float dv = dws[col];
#pragma unroll
            for (int i = 0; i < 4; ++i) {
                float zz = 1.0f / (1.0f + __expf(-az[n2][i]));
                float rr = 1.0f / (1.0f + __expf(-arr[n2][i]));
                float cd = tanhf(axh[n2][i] + rr * ahh[n2][i]);
                float hn = zz * hreg[n2][i] + (1.0f - zz) * cd;
                hreg[n2][i] = hn;
                hs[(q * 4 + i) * HS + col] = f2bf(hn);
                sd[i] += hn * dv;
            }
        }
#pragma unroll
        for (int i = 0; i < 4; ++i) {
            float s = sd[i];
            s += __shfl_xor(s, 1, 64);
            s += __shfl_xor(s, 2, 64);
            s += __shfl_xor(s, 4, 64);
            s += __shfl_xor(s, 8, 64);
            if (c == 0) wpart[t & 1][w][q * 4 + i] = s;
        }

        // stage feat t+1 (xs reads for step t finished at S1)
        if (t + 1 < Tdim && tid < 256) {
            int r = tid >> 4, fi = tid & 15;
            float4 f = *(const float4*)&feat[((size_t)(b0 + r) * Tdim + (t + 1)) * Fdim + fi * 4];
            ushort4 p; p.x = f2bf(f.x); p.y = f2bf(f.y); p.z = f2bf(f.z); p.w = f2bf(f.w);
            *(ushort4*)&xs[r * XS + fi * 4] = p;
        }
        __syncthreads();   // S2: hs/wpart/xs writes visible
    }

    // final dense output for t=95
    {
        int r = lane & 15;
        const float (*wp)[BM] = wpart[(Tdim - 1) & 1];
        float s = dbv;
#pragma unroll
        for (int ww = 0; ww < 8; ++ww) s += wp[ww][r];
        if (w == 0 && lane < BM) outbuf[r * OS + (Tdim - 1)] = s;
    }
    __syncthreads();

    // coalesced dump: out[(b0+r)*96 + tt]
    for (int i = tid; i < BM * Tdim; i += 512) {
        int r = i / Tdim, tt = i - r * Tdim;
        out[(size_t)b0 * Tdim + i] = outbuf[r * OS + tt];
    }
}

extern "C" void kernel_launch(void* const* d_in, const int* in_sizes, int n_in,
                              void* d_out, int out_size, void* d_ws, size_t ws_size,
                              hipStream_t stream) {
    const float* feat       = (const float*)d_in[0];
    const float* init_state = (const float*)d_in[1];
    const float* init_inp   = (const float*)d_in[2];
    const float* Wk         = (const float*)d_in[3];
    const float* Wr         = (const float*)d_in[4];
    const float* ib         = (const float*)d_in[5];
    const float* rb         = (const float*)d_in[6];
    const float* dw         = (const float*)d_in[7];
    const float* db         = (const float*)d_in[8];
    float* out              = (float*)d_out;

    unsigned short* sW = (unsigned short*)d_ws;   // 480 frags * 1 KB = 480 KB

    prep_swz<<<120, 256, 0, stream>>>(Wk, Wr, sW);
    gru_mfma8<<<Bdim / BM, 512, 0, stream>>>(
        feat, init_state, init_inp, sW, Wk, ib, rb, dw, db, out);
}